// Round 1
// baseline (5149.380 us; speedup 1.0000x reference)
//
#include <hip/hip_runtime.h>
#include <hip/hip_bf16.h>

// RWKV TimeMix: B=8, T=4096, C=1024, fp32.
// Pipeline: [gemm_nt<0> x3 fused-lerp] -> [wkv scan + sigmoid gate] -> [gemm_nt<1>]
// Workspace: 3 buffers of B*T*C floats (k, v, r; y overwrites r in-place) = 384 MB.

#define BH 8
#define TT 4096
#define CC 1024

// D[m,n] = sum_c A[m,c] * W[n,c]   (einsum 'btc,dc->btd')
// MODE 0: A[m,c] = lerp(x_prev[m,c], x[m,c], mix[c]); grid.z selects (W,mix,D)
// MODE 1: A = X directly
template<int MODE>
__global__ __launch_bounds__(256)
void gemm_nt(const float* __restrict__ X,
             const float* __restrict__ Wa, const float* __restrict__ Wb, const float* __restrict__ Wc,
             const float* __restrict__ ma, const float* __restrict__ mb, const float* __restrict__ mc,
             float* __restrict__ Da, float* __restrict__ Db, float* __restrict__ Dc)
{
  constexpr int TM = 64, TN = 64, TK = 16;
  constexpr int N = CC, K = CC;

  const float* W; const float* mix; float* D;
  if (MODE == 0) {
    int z = blockIdx.z;
    W   = (z == 0) ? Wa : (z == 1) ? Wb : Wc;
    mix = (z == 0) ? ma : (z == 1) ? mb : mc;
    D   = (z == 0) ? Da : (z == 1) ? Db : Dc;
  } else {
    W = Wa; mix = nullptr; D = Da;
  }

  // stride TM+4 = 68 floats = 272 B: keeps every row 16B-aligned for ds_read_b128
  __shared__ __align__(16) float As[TK][TM + 4];
  __shared__ __align__(16) float Bs[TK][TN + 4];

  const int tid = threadIdx.x;
  const int m0 = blockIdx.y * TM;
  const int n0 = blockIdx.x * TN;

  const int lr  = tid >> 2;        // 0..63: row within tile for staging
  const int lc4 = (tid & 3) * 4;   // 0,4,8,12: float4 slot along k

  const int tm = (tid & 15) * 4;   // micro-tile row base
  const int tn = (tid >> 4) * 4;   // micro-tile col base

  float acc[4][4] = {};

  for (int k0 = 0; k0 < K; k0 += TK) {
    // ---- stage A tile (with fused time-shift lerp in MODE 0)
    {
      const int m = m0 + lr;
      const int c = k0 + lc4;
      float4 xv = *(const float4*)(X + (size_t)m * K + c);
      float4 av;
      if (MODE == 0) {
        const int t = m & (TT - 1);             // m = b*T + t, T power of 2
        float4 xp = make_float4(0.f, 0.f, 0.f, 0.f);
        if (t != 0) xp = *(const float4*)(X + (size_t)(m - 1) * K + c);
        float4 mx = *(const float4*)(mix + c);
        av.x = xp.x + mx.x * (xv.x - xp.x);
        av.y = xp.y + mx.y * (xv.y - xp.y);
        av.z = xp.z + mx.z * (xv.z - xp.z);
        av.w = xp.w + mx.w * (xv.w - xp.w);
      } else {
        av = xv;
      }
      As[lc4 + 0][lr] = av.x; As[lc4 + 1][lr] = av.y;
      As[lc4 + 2][lr] = av.z; As[lc4 + 3][lr] = av.w;
    }
    // ---- stage B tile (W rows n0..n0+63)
    {
      const int n = n0 + lr;
      const int c = k0 + lc4;
      float4 wv = *(const float4*)(W + (size_t)n * K + c);
      Bs[lc4 + 0][lr] = wv.x; Bs[lc4 + 1][lr] = wv.y;
      Bs[lc4 + 2][lr] = wv.z; Bs[lc4 + 3][lr] = wv.w;
    }
    __syncthreads();

    #pragma unroll
    for (int kk = 0; kk < TK; ++kk) {
      float4 a4 = *(const float4*)&As[kk][tm];
      float4 b4 = *(const float4*)&Bs[kk][tn];
      float a[4] = {a4.x, a4.y, a4.z, a4.w};
      float b[4] = {b4.x, b4.y, b4.z, b4.w};
      #pragma unroll
      for (int i = 0; i < 4; ++i)
        #pragma unroll
        for (int j = 0; j < 4; ++j)
          acc[i][j] = fmaf(a[i], b[j], acc[i][j]);
    }
    __syncthreads();
  }

  #pragma unroll
  for (int i = 0; i < 4; ++i) {
    float4 o = make_float4(acc[i][0], acc[i][1], acc[i][2], acc[i][3]);
    *(float4*)(D + (size_t)(m0 + tm + i) * N + (n0 + tn)) = o;
  }
}

// One thread per (b, c) channel lane; sequential over T.
// y (= sigmoid(r) * wkv) overwrites the r buffer in place (read-before-write per element).
__global__ __launch_bounds__(256)
void wkv_scan(const float* __restrict__ kb, const float* __restrict__ vb,
              const float* __restrict__ rb, const float* __restrict__ decay,
              const float* __restrict__ first, float* __restrict__ yb)
{
  const int idx = blockIdx.x * blockDim.x + threadIdx.x;
  if (idx >= BH * CC) return;
  const int b = idx / CC;
  const int c = idx % CC;

  const float w = -__expf(decay[c]);
  const float u = first[c];

  float aa = 0.f, bb = 0.f, pp = -1e38f;
  size_t base = (size_t)b * TT * CC + c;

  for (int t = 0; t < TT; ++t) {
    const float kt = kb[base];
    const float vt = vb[base];
    const float rt = rb[base];

    // output at t (bonus u on current token)
    const float q  = fmaxf(pp, u + kt);
    const float e1 = __expf(pp - q);
    const float e2 = __expf(u + kt - q);
    const float yv = (e1 * aa + e2 * vt) / (e1 * bb + e2);
    const float sr = 1.f / (1.f + __expf(-rt));
    yb[base] = sr * yv;

    // state update with decay w
    const float q2 = fmaxf(pp + w, kt);
    const float f1 = __expf(pp + w - q2);
    const float f2 = __expf(kt - q2);
    aa = f1 * aa + f2 * vt;
    bb = f1 * bb + f2;
    pp = q2;

    base += CC;
  }
}

extern "C" void kernel_launch(void* const* d_in, const int* in_sizes, int n_in,
                              void* d_out, int out_size, void* d_ws, size_t ws_size,
                              hipStream_t stream) {
  const float* x     = (const float*)d_in[0];
  const float* decay = (const float*)d_in[1];
  const float* first = (const float*)d_in[2];
  const float* mk    = (const float*)d_in[3];
  const float* mv    = (const float*)d_in[4];
  const float* mr    = (const float*)d_in[5];
  const float* Wk    = (const float*)d_in[6];
  const float* Wv    = (const float*)d_in[7];
  const float* Wr    = (const float*)d_in[8];
  const float* Wo    = (const float*)d_in[9];
  float* out = (float*)d_out;

  const size_t nbt = (size_t)BH * TT * CC;   // 33,554,432 elements
  float* kbuf = (float*)d_ws;                // needs 3 * nbt * 4 = 384 MB of d_ws
  float* vbuf = kbuf + nbt;
  float* rbuf = vbuf + nbt;

  dim3 blk(256);

  // k, v, r GEMMs with fused time-shift lerp
  dim3 g1(CC / 64, (BH * TT) / 64, 3);
  gemm_nt<0><<<g1, blk, 0, stream>>>(x, Wk, Wv, Wr, mk, mv, mr, kbuf, vbuf, rbuf);

  // WKV scan + sigmoid gate (y overwrites rbuf)
  wkv_scan<<<dim3((BH * CC) / 256), blk, 0, stream>>>(kbuf, vbuf, rbuf, decay, first, rbuf);

  // out = y @ Wo^T
  dim3 g2(CC / 64, (BH * TT) / 64, 1);
  gemm_nt<1><<<g2, blk, 0, stream>>>(rbuf, Wo, nullptr, nullptr,
                                     nullptr, nullptr, nullptr,
                                     out, nullptr, nullptr);
}

// Round 2
// 1229.318 us; speedup vs baseline: 4.1888x; 4.1888x over previous
//
#include <hip/hip_runtime.h>
#include <hip/hip_bf16.h>

// RWKV TimeMix, B=8 T=4096 C=1024 fp32.
// GEMMs via bf16x3 MFMA emulation (hi*hi + hi*lo + lo*hi), WKV via 3-phase chunked scan.
// ws layout: k,v,r fp32 (384MB) | W splits bf16 (16MB) | scan states (6MB) = ~406MB.

#define BH 8
#define TT 4096
#define CC 1024
#define NCH 64
#define CHL (TT / NCH)   // 64

typedef short  short8 __attribute__((ext_vector_type(8)));
typedef unsigned short u16x8 __attribute__((ext_vector_type(8)));
typedef float  f32x4  __attribute__((ext_vector_type(4)));

__device__ __forceinline__ unsigned short f2bf(float f) {
  union { float f; unsigned int u; } v; v.f = f;
  unsigned int u = v.u;
  unsigned int r = (u + 0x7fffu + ((u >> 16) & 1u)) >> 16;  // RNE
  return (unsigned short)r;
}
__device__ __forceinline__ float bf2f(unsigned short h) {
  union { unsigned int u; float f; } v; v.u = ((unsigned int)h) << 16;
  return v.f;
}

#define GLOAD_LDS16(g, l)                                                     \
  __builtin_amdgcn_global_load_lds(                                           \
      (const __attribute__((address_space(1))) unsigned int*)(g),             \
      (__attribute__((address_space(3))) unsigned int*)(l), 16, 0, 0)

// ---- split W matrices into hi/lo bf16 (once, tiny) ----
__global__ __launch_bounds__(256)
void split_w(const float* __restrict__ W0, const float* __restrict__ W1,
             const float* __restrict__ W2, const float* __restrict__ W3,
             unsigned short* __restrict__ out)
{
  int idx = blockIdx.x * 256 + threadIdx.x;      // 4 * 2^20 elements
  int w = idx >> 20;
  int e = idx & (CC * CC - 1);
  const float* src = (w == 0) ? W0 : (w == 1) ? W1 : (w == 2) ? W2 : W3;
  float v = src[e];
  unsigned short h = f2bf(v);
  float lo = v - bf2f(h);
  unsigned short* base = out + (size_t)w * 2 * CC * CC;
  base[e] = h;
  base[CC * CC + e] = f2bf(lo);
}

// ---- bf16x3 MFMA GEMM: D[m,n] = sum_c A[m,c] * W[n,c] ----
// MODE 0: A = lerp(x_prev, x, mix), z in {0,1,2} selects (W,mix,D). MODE 1: A = X.
// 128x128 tile, BK=32, 4 waves, 64x64 per wave (4x4 frags of 16x16x32).
// LDS swizzle: phys_kq = kq_log ^ ((row>>1)&3); applied on A ds_write, B global src, and reads.
template<int MODE>
__global__ __launch_bounds__(256, 2)
void gemm_bf16x3(const float* __restrict__ X,
                 const unsigned short* __restrict__ Wsp,
                 const float* __restrict__ ma, const float* __restrict__ mb, const float* __restrict__ mc,
                 float* __restrict__ Da, float* __restrict__ Db, float* __restrict__ Dc)
{
  constexpr int BM = 128, BN = 128, BK = 32;

  const unsigned short *Whi, *Wlo; const float* mix; float* D;
  if (MODE == 0) {
    int z = blockIdx.z;
    Whi = Wsp + (size_t)z * 2 * CC * CC; Wlo = Whi + CC * CC;
    mix = (z == 0) ? ma : (z == 1) ? mb : mc;
    D   = (z == 0) ? Da : (z == 1) ? Db : Dc;
  } else {
    Whi = Wsp; Wlo = Whi + CC * CC; mix = nullptr; D = Da;
  }

  __shared__ __align__(16) unsigned short Ah[BM][BK];
  __shared__ __align__(16) unsigned short Al[BM][BK];
  __shared__ __align__(16) unsigned short Bh[BN][BK];
  __shared__ __align__(16) unsigned short Bl[BN][BK];

  const int tid = threadIdx.x;
  const int m0 = blockIdx.y * BM, n0 = blockIdx.x * BN;

  const int srow = tid >> 1, shalf = tid & 1;     // A staging: row, 16-col half
  const int wave = tid >> 6, lane = tid & 63;
  const int wm = wave & 1, wn = wave >> 1;        // wave -> 64x64 quadrant
  const int lr = lane & 15, kg = lane >> 4;       // frag row/col, k-group

  f32x4 acc[4][4] = {};

  const int gm = m0 + srow;
  const float* xrow = X + (size_t)gm * CC;
  const float* prow = xrow - CC;
  const bool has_prev = (MODE == 0) && ((gm & (TT - 1)) != 0);

  for (int k0 = 0; k0 < CC; k0 += BK) {
    // ---- A: global->reg (+lerp), split to hi/lo bf16 (before barrier: overlaps prev MFMA)
    float va[16];
    const int cbase = k0 + shalf * 16;
    #pragma unroll
    for (int i = 0; i < 4; ++i)
      *(float4*)(va + i * 4) = *(const float4*)(xrow + cbase + i * 4);
    if (MODE == 0) {
      #pragma unroll
      for (int i = 0; i < 4; ++i) {
        float4 xp = has_prev ? *(const float4*)(prow + cbase + i * 4)
                             : make_float4(0.f, 0.f, 0.f, 0.f);
        float4 mx = *(const float4*)(mix + cbase + i * 4);
        float* pv = va + i * 4;
        pv[0] = xp.x + mx.x * (pv[0] - xp.x);
        pv[1] = xp.y + mx.y * (pv[1] - xp.y);
        pv[2] = xp.z + mx.z * (pv[2] - xp.z);
        pv[3] = xp.w + mx.w * (pv[3] - xp.w);
      }
    }
    u16x8 hp0, hp1, lp0, lp1;
    #pragma unroll
    for (int i = 0; i < 8; ++i) {
      unsigned short h0 = f2bf(va[i]);     hp0[i] = h0;
      lp0[i] = f2bf(va[i] - bf2f(h0));
      unsigned short h1 = f2bf(va[8 + i]); hp1[i] = h1;
      lp1[i] = f2bf(va[8 + i] - bf2f(h1));
    }

    __syncthreads();   // previous compute done reading LDS

    // A ds_write (swizzled)
    {
      const int f = (srow >> 1) & 3;
      const int q0 = ((shalf * 2)     ^ f) * 8;
      const int q1 = ((shalf * 2 + 1) ^ f) * 8;
      *(u16x8*)&Ah[srow][q0] = hp0;
      *(u16x8*)&Ah[srow][q1] = hp1;
      *(u16x8*)&Al[srow][q0] = lp0;
      *(u16x8*)&Al[srow][q1] = lp1;
    }
    // B global->LDS direct (linear LDS dest, inverse-swizzled global source)
    #pragma unroll
    for (int i = 0; i < 2; ++i) {
      int slot = i * 256 + tid;               // 512 slots of 16B per component
      int brow = slot >> 2, bq = slot & 3;
      int kql = bq ^ ((brow >> 1) & 3);
      const unsigned short* gh = Whi + (size_t)(n0 + brow) * CC + k0 + kql * 8;
      const unsigned short* gl = Wlo + (size_t)(n0 + brow) * CC + k0 + kql * 8;
      unsigned short* lh = &Bh[0][0] + (size_t)(i * 256 + wave * 64) * 8;  // wave-uniform base
      unsigned short* ll = &Bl[0][0] + (size_t)(i * 256 + wave * 64) * 8;
      GLOAD_LDS16(gh, lh);
      GLOAD_LDS16(gl, ll);
    }

    __syncthreads();   // drains lgkm + vmcnt (compiler-enforced)

    // ---- fragments + 48 MFMA
    short8 ah[4], al[4], bh[4], bl[4];
    #pragma unroll
    for (int fm = 0; fm < 4; ++fm) {
      int row = wm * 64 + fm * 16 + lr;
      int ph = (kg ^ ((row >> 1) & 3)) * 8;
      ah[fm] = *(const short8*)&Ah[row][ph];
      al[fm] = *(const short8*)&Al[row][ph];
    }
    #pragma unroll
    for (int fn = 0; fn < 4; ++fn) {
      int row = wn * 64 + fn * 16 + lr;
      int ph = (kg ^ ((row >> 1) & 3)) * 8;
      bh[fn] = *(const short8*)&Bh[row][ph];
      bl[fn] = *(const short8*)&Bl[row][ph];
    }
    #pragma unroll
    for (int fm = 0; fm < 4; ++fm)
      #pragma unroll
      for (int fn = 0; fn < 4; ++fn) {
        acc[fm][fn] = __builtin_amdgcn_mfma_f32_16x16x32_bf16(ah[fm], bh[fn], acc[fm][fn], 0, 0, 0);
        acc[fm][fn] = __builtin_amdgcn_mfma_f32_16x16x32_bf16(ah[fm], bl[fn], acc[fm][fn], 0, 0, 0);
        acc[fm][fn] = __builtin_amdgcn_mfma_f32_16x16x32_bf16(al[fm], bh[fn], acc[fm][fn], 0, 0, 0);
      }
  }

  // ---- epilogue: C/D map col=lane&15, row=(lane>>4)*4+reg
  #pragma unroll
  for (int fm = 0; fm < 4; ++fm) {
    #pragma unroll
    for (int fn = 0; fn < 4; ++fn) {
      const int col  = n0 + wn * 64 + fn * 16 + lr;
      const int rowb = m0 + wm * 64 + fm * 16 + kg * 4;
      #pragma unroll
      for (int r = 0; r < 4; ++r)
        D[(size_t)(rowb + r) * CC + col] = acc[fm][fn][r];
    }
  }
}

// ---- WKV chunked scan ----
// Phase A: per (b,chunk,c) local state from zero over CHL steps.
__global__ __launch_bounds__(256)
void wkv_phase_a(const float* __restrict__ kb, const float* __restrict__ vb,
                 const float* __restrict__ decay,
                 float* __restrict__ SA, float* __restrict__ SB, float* __restrict__ SP)
{
  const int idx = blockIdx.x * 256 + threadIdx.x;   // (b*NCH + ch)*CC + c
  const int c  = idx & (CC - 1);
  const int bc = idx >> 10;
  const int ch = bc & (NCH - 1);
  const int b  = bc >> 6;
  const float w = -__expf(decay[c]);
  float aa = 0.f, bb = 0.f, pp = -1e38f;
  size_t base = ((size_t)b * TT + (size_t)ch * CHL) * CC + c;
  #pragma unroll 4
  for (int t = 0; t < CHL; ++t) {
    const float kt = kb[base], vt = vb[base];
    const float q2 = fmaxf(pp + w, kt);
    const float f1 = __expf(pp + w - q2);
    const float f2 = __expf(kt - q2);
    aa = f1 * aa + f2 * vt; bb = f1 * bb + f2; pp = q2;
    base += CC;
  }
  SA[idx] = aa; SB[idx] = bb; SP[idx] = pp;
}

// Phase B: sequential combine over chunks; arrays become INCOMING (exclusive-prefix) states.
__global__ __launch_bounds__(256)
void wkv_combine(float* __restrict__ SA, float* __restrict__ SB, float* __restrict__ SP,
                 const float* __restrict__ decay)
{
  const int idx = blockIdx.x * 256 + threadIdx.x;   // b*CC + c
  const int c = idx & (CC - 1);
  const int b = idx >> 10;
  const float w  = -__expf(decay[c]);
  const float wL = w * (float)CHL;
  float aa = 0.f, bb = 0.f, pp = -1e38f;
  for (int ch = 0; ch < NCH; ++ch) {
    const size_t s = ((size_t)b * NCH + ch) * CC + c;
    const float la = SA[s], lb = SB[s], lp = SP[s];
    SA[s] = aa; SB[s] = bb; SP[s] = pp;
    const float pw = pp + wL;
    const float q  = fmaxf(pw, lp);
    const float e1 = __expf(pw - q);
    const float e2 = __expf(lp - q);
    aa = e1 * aa + e2 * la; bb = e1 * bb + e2 * lb; pp = q;
  }
}

// Phase C: re-run each chunk with incoming state, emit y = sigmoid(r)*wkv (in-place over r).
__global__ __launch_bounds__(256)
void wkv_phase_c(const float* __restrict__ kb, const float* __restrict__ vb,
                 const float* __restrict__ rb, const float* __restrict__ decay,
                 const float* __restrict__ first,
                 const float* __restrict__ SA, const float* __restrict__ SB,
                 const float* __restrict__ SP, float* __restrict__ yb)
{
  const int idx = blockIdx.x * 256 + threadIdx.x;
  const int c  = idx & (CC - 1);
  const int bc = idx >> 10;
  const int ch = bc & (NCH - 1);
  const int b  = bc >> 6;
  const float w = -__expf(decay[c]);
  const float u = first[c];
  float aa = SA[idx], bb = SB[idx], pp = SP[idx];
  size_t base = ((size_t)b * TT + (size_t)ch * CHL) * CC + c;
  #pragma unroll 4
  for (int t = 0; t < CHL; ++t) {
    const float kt = kb[base], vt = vb[base], rt = rb[base];
    const float q  = fmaxf(pp, u + kt);
    const float e1 = __expf(pp - q);
    const float e2 = __expf(u + kt - q);
    const float yv = (e1 * aa + e2 * vt) / (e1 * bb + e2);
    const float sr = 1.f / (1.f + __expf(-rt));
    yb[base] = sr * yv;
    const float q2 = fmaxf(pp + w, kt);
    const float f1 = __expf(pp + w - q2);
    const float f2 = __expf(kt - q2);
    aa = f1 * aa + f2 * vt; bb = f1 * bb + f2; pp = q2;
    base += CC;
  }
}

extern "C" void kernel_launch(void* const* d_in, const int* in_sizes, int n_in,
                              void* d_out, int out_size, void* d_ws, size_t ws_size,
                              hipStream_t stream) {
  const float* x     = (const float*)d_in[0];
  const float* decay = (const float*)d_in[1];
  const float* first = (const float*)d_in[2];
  const float* mk    = (const float*)d_in[3];
  const float* mv    = (const float*)d_in[4];
  const float* mr    = (const float*)d_in[5];
  const float* Wk    = (const float*)d_in[6];
  const float* Wv    = (const float*)d_in[7];
  const float* Wr    = (const float*)d_in[8];
  const float* Wo    = (const float*)d_in[9];
  float* out = (float*)d_out;

  const size_t nbt = (size_t)BH * TT * CC;
  float* kbuf = (float*)d_ws;
  float* vbuf = kbuf + nbt;
  float* rbuf = vbuf + nbt;
  unsigned short* Wsp = (unsigned short*)(rbuf + nbt);   // 8 * CC*CC ushorts
  float* SA = (float*)(Wsp + (size_t)8 * CC * CC);
  float* SB = SA + (size_t)BH * NCH * CC;
  float* SP = SB + (size_t)BH * NCH * CC;

  dim3 blk(256);

  // 1) split W into hi/lo bf16
  split_w<<<dim3(4 * CC * CC / 256), blk, 0, stream>>>(Wk, Wv, Wr, Wo, Wsp);

  // 2) k,v,r GEMMs (fused lerp + on-the-fly bf16x3 split of A)
  dim3 g1(CC / 128, (BH * TT) / 128, 3);
  gemm_bf16x3<0><<<g1, blk, 0, stream>>>(x, Wsp, mk, mv, mr, kbuf, vbuf, rbuf);

  // 3) chunked WKV scan + sigmoid gate (y overwrites rbuf)
  const int nscan = BH * NCH * CC;
  wkv_phase_a<<<dim3(nscan / 256), blk, 0, stream>>>(kbuf, vbuf, decay, SA, SB, SP);
  wkv_combine<<<dim3(BH * CC / 256), blk, 0, stream>>>(SA, SB, SP, decay);
  wkv_phase_c<<<dim3(nscan / 256), blk, 0, stream>>>(kbuf, vbuf, rbuf, decay, first,
                                                     SA, SB, SP, rbuf);

  // 4) out = y @ Wo^T
  dim3 g2(CC / 128, (BH * TT) / 128, 1);
  gemm_bf16x3<1><<<g2, blk, 0, stream>>>(rbuf, Wsp + (size_t)3 * 2 * CC * CC,
                                         nullptr, nullptr, nullptr,
                                         out, nullptr, nullptr);
}

// Round 4
// 1108.608 us; speedup vs baseline: 4.6449x; 1.1089x over previous
//
#include <hip/hip_runtime.h>
#include <hip/hip_bf16.h>
#include <hip/hip_fp16.h>

// RWKV TimeMix, B=8 T=4096 C=1024 fp32.
// Round 4: sequential-z lerp+split prepass (128MiB scratch reused) + concat-K
// (K=3072) bf16 MFMA GEMM with 3-buffer LDS rotation, counted vmcnt, setprio.
// Outputs: k fp32, v/r fp16. ws layout = 425,721,856 B == round-2-proven size.

#define BH 8
#define TT 4096
#define CC 1024
#define NCH 64
#define CHL (TT / NCH)

typedef short          short8 __attribute__((ext_vector_type(8)));
typedef unsigned short u16x8  __attribute__((ext_vector_type(8)));
typedef float          f32x4  __attribute__((ext_vector_type(4)));
typedef unsigned short ushort_t;

__device__ __forceinline__ unsigned short f2bf(float f) {
  union { float f; unsigned int u; } v; v.f = f;
  unsigned int u = v.u;
  return (unsigned short)((u + 0x7fffu + ((u >> 16) & 1u)) >> 16);  // RNE
}
__device__ __forceinline__ float bf2f(unsigned short h) {
  union { unsigned int u; float f; } v; v.u = ((unsigned int)h) << 16;
  return v.f;
}

#define GLOAD_LDS16(g, l)                                                     \
  __builtin_amdgcn_global_load_lds(                                           \
      (const __attribute__((address_space(1))) unsigned int*)(g),             \
      (__attribute__((address_space(3))) unsigned int*)(l), 16, 0, 0)

#define BARRIER() do { asm volatile("" ::: "memory");                        \
                       __builtin_amdgcn_s_barrier();                          \
                       asm volatile("" ::: "memory"); } while (0)

// ---- split 4 W matrices into hi/lo bf16 (8 bufs of CC*CC) ----
__global__ __launch_bounds__(256)
void split_w(const float* __restrict__ W0, const float* __restrict__ W1,
             const float* __restrict__ W2, const float* __restrict__ W3,
             ushort_t* __restrict__ out)
{
  int idx = blockIdx.x * 256 + threadIdx.x;
  int w = idx >> 20;
  int e = idx & (CC * CC - 1);
  const float* src = (w == 0) ? W0 : (w == 1) ? W1 : (w == 2) ? W2 : W3;
  float v = src[e];
  unsigned short h = f2bf(v);
  ushort_t* base = out + (size_t)w * 2 * CC * CC;
  base[e] = h;
  base[CC * CC + e] = f2bf(v - bf2f(h));
}

// ---- time-shift lerp + hi/lo split for ONE mix (reused scratch) ----
__global__ __launch_bounds__(256)
void lerp_split_one(const float* __restrict__ x, const float* __restrict__ mix,
                    ushort_t* __restrict__ oh, ushort_t* __restrict__ ol)
{
  const int idx = blockIdx.x * 256 + threadIdx.x;   // one float4 per thread
  const int m = idx >> 8;
  const int c = (idx & 255) * 4;
  const size_t e = (size_t)m * CC + c;
  float4 xv = *(const float4*)(x + e);
  float4 xp = make_float4(0.f, 0.f, 0.f, 0.f);
  if ((m & (TT - 1)) != 0) xp = *(const float4*)(x + e - CC);
  float4 mx = *(const float4*)(mix + c);
  float a0 = xp.x + mx.x * (xv.x - xp.x);
  float a1 = xp.y + mx.y * (xv.y - xp.y);
  float a2 = xp.z + mx.z * (xv.z - xp.z);
  float a3 = xp.w + mx.w * (xv.w - xp.w);
  ushort_t h0 = f2bf(a0), h1 = f2bf(a1), h2 = f2bf(a2), h3 = f2bf(a3);
  *(ushort4*)(oh + e) = make_ushort4(h0, h1, h2, h3);
  *(ushort4*)(ol + e) = make_ushort4(f2bf(a0 - bf2f(h0)), f2bf(a1 - bf2f(h1)),
                                     f2bf(a2 - bf2f(h2)), f2bf(a3 - bf2f(h3)));
}

// ---- bf16 GEMM, logical K=3072 = [Ah|Ah|Al] x [Bh|Bl|Bh] (bf16x3) ----
// M=32768 N=1024. 256x256 tile, BK=32, 512 thr (8 waves 2Mx4N), per-wave 128x64.
// 3-buffer LDS (96KiB); stage tile t+2 during tile t; counted vmcnt(4).
// Swizzle: phys_kq = kq ^ ((row>>1)&3) on staging SOURCE addr and frag reads.
// EPI: 0 -> fp32 D, 1 -> fp16 D.
template<int EPI>
__global__ __launch_bounds__(512, 2)
void gemm_cat3(const ushort_t* __restrict__ Ah, const ushort_t* __restrict__ Al,
               const ushort_t* __restrict__ Bh, const ushort_t* __restrict__ Bl,
               void* __restrict__ Dv)
{
  constexpr int BK = 32;
  constexpr int NT = 96;   // 3 comps x 32 k-tiles

  __shared__ __align__(16) ushort_t lds[3][2][8192];   // [buf][A/B][256*32]

  const int tid  = threadIdx.x;
  const int wave = tid >> 6, lane = tid & 63;
  const int wm = wave & 1, wn = wave >> 1;
  const int lr = lane & 15, kg = lane >> 4;

  // XCD-aware bijective swizzle (nwg=512, 512%8==0)
  const int bid = blockIdx.x;
  const int swz = (bid & 7) * 64 + (bid >> 3);
  const int m0 = (swz >> 2) * 256;     // 128 m-blocks
  const int n0 = (swz & 3) * 256;      // 4 n-blocks

  f32x4 acc[8][4] = {};

  // stage-issue: i=0,1 -> A halves; i=2,3 -> B halves (8KiB per issue)
  auto issue = [&](int t, int i) {
    const int comp = t >> 5;
    const int kin  = (t & 31) * BK;
    const int op   = i >> 1;
    const int half = i & 1;
    const ushort_t* g0 = op ? ((comp == 1) ? Bl : Bh)
                            : ((comp == 2) ? Al : Ah);
    const int r0 = op ? n0 : m0;
    const int Lb  = half * 8192 + tid * 16;       // byte within 16KiB op-tile
    const int row = Lb >> 6;
    const int kq  = ((Lb >> 4) & 3) ^ ((row >> 1) & 3);
    const ushort_t* src = g0 + (size_t)(r0 + row) * CC + kin + kq * 8;
    ushort_t* dst = &lds[t % 3][op][half * 4096 + wave * 512];  // wave-uniform base
    GLOAD_LDS16(src, dst);
  };
  auto rdA = [&](int b, int fm) -> short8 {
    const int row = wm * 128 + fm * 16 + lr;
    const int kq  = kg ^ ((row >> 1) & 3);
    return *(const short8*)&lds[b][0][row * BK + kq * 8];
  };
  auto rdB = [&](int b, int fn) -> short8 {
    const int row = wn * 64 + fn * 16 + lr;
    const int kq  = kg ^ ((row >> 1) & 3);
    return *(const short8*)&lds[b][1][row * BK + kq * 8];
  };

  // prologue: stage tiles 0,1; wait for tile 0 (4 oldest of 8)
  #pragma unroll
  for (int tt = 0; tt < 2; ++tt)
    #pragma unroll
    for (int i = 0; i < 4; ++i) issue(tt, i);
  asm volatile("s_waitcnt vmcnt(4)" ::: "memory");
  BARRIER();

  for (int t = 0; t < NT; ++t) {
    const int b = t % 3;
    const bool pre = (t + 2 < NT);

    // phase 0: read B + A(0..3), stage halves 0 of t+2
    short8 bfr[4], afr[4];
    #pragma unroll
    for (int fn = 0; fn < 4; ++fn) bfr[fn] = rdB(b, fn);
    #pragma unroll
    for (int i = 0; i < 4; ++i) afr[i] = rdA(b, i);
    if (pre) { issue(t + 2, 0); issue(t + 2, 2); }
    BARRIER();
    __builtin_amdgcn_s_setprio(1);
    #pragma unroll
    for (int i = 0; i < 4; ++i)
      #pragma unroll
      for (int fn = 0; fn < 4; ++fn)
        acc[i][fn] = __builtin_amdgcn_mfma_f32_16x16x32_bf16(afr[i], bfr[fn], acc[i][fn], 0, 0, 0);
    __builtin_amdgcn_s_setprio(0);
    BARRIER();

    // phase 1: read A(4..7), stage halves 1 of t+2, counted wait
    #pragma unroll
    for (int i = 0; i < 4; ++i) afr[i] = rdA(b, 4 + i);
    if (pre) { issue(t + 2, 1); issue(t + 2, 3); }
    BARRIER();
    __builtin_amdgcn_s_setprio(1);
    #pragma unroll
    for (int i = 0; i < 4; ++i)
      #pragma unroll
      for (int fn = 0; fn < 4; ++fn)
        acc[4 + i][fn] = __builtin_amdgcn_mfma_f32_16x16x32_bf16(afr[i], bfr[fn], acc[4 + i][fn], 0, 0, 0);
    __builtin_amdgcn_s_setprio(0);
    if (pre) { asm volatile("s_waitcnt vmcnt(4)" ::: "memory"); }
    else     { asm volatile("s_waitcnt vmcnt(0)" ::: "memory"); }
    BARRIER();
  }

  // epilogue: C/D map col=lane&15, row=(lane>>4)*4+reg
  float*  Df = (float*)Dv;
  __half* Dh = (__half*)Dv;
  #pragma unroll
  for (int fm = 0; fm < 8; ++fm)
    #pragma unroll
    for (int fn = 0; fn < 4; ++fn) {
      const int col  = n0 + wn * 64 + fn * 16 + lr;
      const int rowb = m0 + wm * 128 + fm * 16 + kg * 4;
      #pragma unroll
      for (int r = 0; r < 4; ++r) {
        if (EPI == 0) Df[(size_t)(rowb + r) * CC + col] = acc[fm][fn][r];
        else          Dh[(size_t)(rowb + r) * CC + col] = __float2half(acc[fm][fn][r]);
      }
    }
}

// ---- WKV chunked scan ----
__global__ __launch_bounds__(256)
void wkv_phase_a(const float* __restrict__ kb, const __half* __restrict__ vb,
                 const float* __restrict__ decay,
                 float* __restrict__ SA, float* __restrict__ SB, float* __restrict__ SP)
{
  const int idx = blockIdx.x * 256 + threadIdx.x;
  const int c  = idx & (CC - 1);
  const int bc = idx >> 10;
  const int ch = bc & (NCH - 1);
  const int b  = bc >> 6;
  const float w = -__expf(decay[c]);
  float aa = 0.f, bb = 0.f, pp = -1e38f;
  size_t base = ((size_t)b * TT + (size_t)ch * CHL) * CC + c;
  #pragma unroll 4
  for (int t = 0; t < CHL; ++t) {
    const float kt = kb[base];
    const float vt = __half2float(vb[base]);
    const float q2 = fmaxf(pp + w, kt);
    const float f1 = __expf(pp + w - q2);
    const float f2 = __expf(kt - q2);
    aa = f1 * aa + f2 * vt; bb = f1 * bb + f2; pp = q2;
    base += CC;
  }
  SA[idx] = aa; SB[idx] = bb; SP[idx] = pp;
}

__global__ __launch_bounds__(256)
void wkv_combine(float* __restrict__ SA, float* __restrict__ SB, float* __restrict__ SP,
                 const float* __restrict__ decay)
{
  const int idx = blockIdx.x * 256 + threadIdx.x;
  const int c = idx & (CC - 1);
  const int b = idx >> 10;
  const float w  = -__expf(decay[c]);
  const float wL = w * (float)CHL;
  float aa = 0.f, bb = 0.f, pp = -1e38f;
  for (int ch = 0; ch < NCH; ++ch) {
    const size_t s = ((size_t)b * NCH + ch) * CC + c;
    const float la = SA[s], lb = SB[s], lp = SP[s];
    SA[s] = aa; SB[s] = bb; SP[s] = pp;
    const float pw = pp + wL;
    const float q  = fmaxf(pw, lp);
    const float e1 = __expf(pw - q);
    const float e2 = __expf(lp - q);
    aa = e1 * aa + e2 * la; bb = e1 * bb + e2 * lb; pp = q;
  }
}

// Phase C: re-run chunk with incoming state; y = sigmoid(r)*wkv as bf16 hi/lo.
__global__ __launch_bounds__(256)
void wkv_phase_c(const float* __restrict__ kb, const __half* __restrict__ vb,
                 const __half* __restrict__ rb, const float* __restrict__ decay,
                 const float* __restrict__ first,
                 const float* __restrict__ SA, const float* __restrict__ SB,
                 const float* __restrict__ SP,
                 ushort_t* __restrict__ yh, ushort_t* __restrict__ yl)
{
  const int idx = blockIdx.x * 256 + threadIdx.x;
  const int c  = idx & (CC - 1);
  const int bc = idx >> 10;
  const int ch = bc & (NCH - 1);
  const int b  = bc >> 6;
  const float w = -__expf(decay[c]);
  const float u = first[c];
  float aa = SA[idx], bb = SB[idx], pp = SP[idx];
  size_t base = ((size_t)b * TT + (size_t)ch * CHL) * CC + c;
  #pragma unroll 4
  for (int t = 0; t < CHL; ++t) {
    const float kt = kb[base];
    const float vt = __half2float(vb[base]);
    const float rt = __half2float(rb[base]);
    const float q  = fmaxf(pp, u + kt);
    const float e1 = __expf(pp - q);
    const float e2 = __expf(u + kt - q);
    const float yv = (e1 * aa + e2 * vt) / (e1 * bb + e2);
    const float sr = 1.f / (1.f + __expf(-rt));
    const float y  = sr * yv;
    const unsigned short h = f2bf(y);
    yh[base] = h;
    yl[base] = f2bf(y - bf2f(h));
    const float q2 = fmaxf(pp + w, kt);
    const float f1 = __expf(pp + w - q2);
    const float f2 = __expf(kt - q2);
    aa = f1 * aa + f2 * vt; bb = f1 * bb + f2; pp = q2;
    base += CC;
  }
}

extern "C" void kernel_launch(void* const* d_in, const int* in_sizes, int n_in,
                              void* d_out, int out_size, void* d_ws, size_t ws_size,
                              hipStream_t stream) {
  const float* x     = (const float*)d_in[0];
  const float* decay = (const float*)d_in[1];
  const float* first = (const float*)d_in[2];
  const float* mk    = (const float*)d_in[3];
  const float* mv    = (const float*)d_in[4];
  const float* mr    = (const float*)d_in[5];
  const float* Wk    = (const float*)d_in[6];
  const float* Wv    = (const float*)d_in[7];
  const float* Wr    = (const float*)d_in[8];
  const float* Wo    = (const float*)d_in[9];
  float* out = (float*)d_out;

  const size_t nbt = (size_t)BH * TT * CC;       // 33,554,432
  const size_t WS  = (size_t)CC * CC;            // 1,048,576
  // ws layout (bytes), total 425,721,856 == round-2-proven usage:
  char* p = (char*)d_ws;
  float*    kbuf = (float*)   (p);                               // 134,217,728
  __half*   vbuf = (__half*)  (p + 134217728);                   //  67,108,864
  __half*   rbuf = (__half*)  (p + 201326592);                   //  67,108,864
  ushort_t* Asch = (ushort_t*)(p + 268435456);                   //  67,108,864 (Ah)
  ushort_t* Ascl = (ushort_t*)(p + 335544320);                   //  67,108,864 (Al)
  ushort_t* Wsp  = (ushort_t*)(p + 402653184);                   //  16,777,216 (8 bufs)
  float*    SA   = (float*)   (p + 419430400);                   //   2,097,152
  float*    SB   = (float*)   (p + 421527552);
  float*    SP   = (float*)   (p + 423624704);

  dim3 blk(256);
  const dim3 ggrid(512), gblk(512);
  const unsigned lerpg = (unsigned)(nbt / 4 / 256);

  // 1) weight splits (Wk,Wv,Wr,Wo -> 8 bufs)
  split_w<<<dim3(4 * CC * CC / 256), blk, 0, stream>>>(Wk, Wv, Wr, Wo, Wsp);

  // 2) sequential z: lerp+split into shared scratch, then concat-K GEMM
  lerp_split_one<<<lerpg, blk, 0, stream>>>(x, mk, Asch, Ascl);
  gemm_cat3<0><<<ggrid, gblk, 0, stream>>>(Asch, Ascl, Wsp + 0 * WS, Wsp + 1 * WS, kbuf);
  lerp_split_one<<<lerpg, blk, 0, stream>>>(x, mv, Asch, Ascl);
  gemm_cat3<1><<<ggrid, gblk, 0, stream>>>(Asch, Ascl, Wsp + 2 * WS, Wsp + 3 * WS, vbuf);
  lerp_split_one<<<lerpg, blk, 0, stream>>>(x, mr, Asch, Ascl);
  gemm_cat3<1><<<ggrid, gblk, 0, stream>>>(Asch, Ascl, Wsp + 4 * WS, Wsp + 5 * WS, rbuf);

  // 3) chunked WKV scan; y-splits overwrite the A scratch (dead)
  const int nscan = BH * NCH * CC;
  wkv_phase_a<<<dim3(nscan / 256), blk, 0, stream>>>(kbuf, vbuf, decay, SA, SB, SP);
  wkv_combine<<<dim3(BH * CC / 256), blk, 0, stream>>>(SA, SB, SP, decay);
  wkv_phase_c<<<dim3(nscan / 256), blk, 0, stream>>>(kbuf, vbuf, rbuf, decay, first,
                                                     SA, SB, SP, Asch, Ascl);

  // 4) out = y @ Wo^T
  gemm_cat3<0><<<ggrid, gblk, 0, stream>>>(Asch, Ascl, Wsp + 6 * WS, Wsp + 7 * WS, out);
}

// Round 5
// 1055.503 us; speedup vs baseline: 4.8786x; 1.0503x over previous
//
#include <hip/hip_runtime.h>
#include <hip/hip_bf16.h>
#include <hip/hip_fp16.h>

// RWKV TimeMix, B=8 T=4096 C=1024 fp32.
// Round 5: GEMM moved to 8-phase counted-vmcnt schedule (m201-class):
// BK=64, 2 LDS bufs x 4 regions (A-ks0,B-ks0,A-ks1,B-ks1; each 256x32, r4's
// proven swizzle), 4 phases/K-step, vmcnt(8) steady-state, setprio around MFMA.
// Everything else identical to round 4. ws = 425,721,856 B (proven).

#define BH 8
#define TT 4096
#define CC 1024
#define NCH 64
#define CHL (TT / NCH)

typedef short          short8 __attribute__((ext_vector_type(8)));
typedef float          f32x4  __attribute__((ext_vector_type(4)));
typedef unsigned short ushort_t;

__device__ __forceinline__ unsigned short f2bf(float f) {
  union { float f; unsigned int u; } v; v.f = f;
  unsigned int u = v.u;
  return (unsigned short)((u + 0x7fffu + ((u >> 16) & 1u)) >> 16);  // RNE
}
__device__ __forceinline__ float bf2f(unsigned short h) {
  union { unsigned int u; float f; } v; v.u = ((unsigned int)h) << 16;
  return v.f;
}

#define GLOAD_LDS16(g, l)                                                     \
  __builtin_amdgcn_global_load_lds(                                           \
      (const __attribute__((address_space(1))) unsigned int*)(g),             \
      (__attribute__((address_space(3))) unsigned int*)(l), 16, 0, 0)

#define BARRIER() do { asm volatile("" ::: "memory");                        \
                       __builtin_amdgcn_s_barrier();                          \
                       asm volatile("" ::: "memory"); } while (0)

#define LGKM0() do { asm volatile("s_waitcnt lgkmcnt(0)" ::: "memory");      \
                     __builtin_amdgcn_sched_barrier(0); } while (0)

// ---- split 4 W matrices into hi/lo bf16 (8 bufs of CC*CC) ----
__global__ __launch_bounds__(256)
void split_w(const float* __restrict__ W0, const float* __restrict__ W1,
             const float* __restrict__ W2, const float* __restrict__ W3,
             ushort_t* __restrict__ out)
{
  int idx = blockIdx.x * 256 + threadIdx.x;
  int w = idx >> 20;
  int e = idx & (CC * CC - 1);
  const float* src = (w == 0) ? W0 : (w == 1) ? W1 : (w == 2) ? W2 : W3;
  float v = src[e];
  unsigned short h = f2bf(v);
  ushort_t* base = out + (size_t)w * 2 * CC * CC;
  base[e] = h;
  base[CC * CC + e] = f2bf(v - bf2f(h));
}

// ---- time-shift lerp + hi/lo split for ONE mix (reused scratch) ----
__global__ __launch_bounds__(256)
void lerp_split_one(const float* __restrict__ x, const float* __restrict__ mix,
                    ushort_t* __restrict__ oh, ushort_t* __restrict__ ol)
{
  const int idx = blockIdx.x * 256 + threadIdx.x;   // one float4 per thread
  const int m = idx >> 8;
  const int c = (idx & 255) * 4;
  const size_t e = (size_t)m * CC + c;
  float4 xv = *(const float4*)(x + e);
  float4 xp = make_float4(0.f, 0.f, 0.f, 0.f);
  if ((m & (TT - 1)) != 0) xp = *(const float4*)(x + e - CC);
  float4 mx = *(const float4*)(mix + c);
  float a0 = xp.x + mx.x * (xv.x - xp.x);
  float a1 = xp.y + mx.y * (xv.y - xp.y);
  float a2 = xp.z + mx.z * (xv.z - xp.z);
  float a3 = xp.w + mx.w * (xv.w - xp.w);
  ushort_t h0 = f2bf(a0), h1 = f2bf(a1), h2 = f2bf(a2), h3 = f2bf(a3);
  *(ushort4*)(oh + e) = make_ushort4(h0, h1, h2, h3);
  *(ushort4*)(ol + e) = make_ushort4(f2bf(a0 - bf2f(h0)), f2bf(a1 - bf2f(h1)),
                                     f2bf(a2 - bf2f(h2)), f2bf(a3 - bf2f(h3)));
}

// ---- bf16 GEMM, logical K=3072 = [Ah|Ah|Al] x [Bh|Bl|Bh] (bf16x3) ----
// M=32768 N=1024. 256x256 tile, BK=64, 512 thr (8 waves 2Mx4N), per-wave 128x64.
// 8-phase (4 phases per K-step of 64, 2 K-steps per dbuf pair):
//   P: {ds_read frags | stage 1 region (2 gload_lds) | barrier | lgkmcnt(0) |
//       setprio(1) 16xMFMA setprio(0) | [vmcnt(8)] | barrier}
// Regions per buf: 0=A-ks0, 1=B-ks0, 2=A-ks1, 3=B-ks1; each [256 rows][32 k]
// with swizzle phys_q = q ^ ((row>>1)&3) (measured conflict-free in r2/r4).
// Stage plan: P1:(s+1,A1) P2:(s+1,B1) P3:(s+2,A0) P4:(s+2,B0).
// Waits: end-P2 vmcnt(8) (s<NS-1) else 0; end-P4 vmcnt(8) (s<NS-2), 4 (s==NS-2).
template<int EPI>
__global__ __launch_bounds__(512, 2)
void gemm_cat3(const ushort_t* __restrict__ Ah, const ushort_t* __restrict__ Al,
               const ushort_t* __restrict__ Bh, const ushort_t* __restrict__ Bl,
               void* __restrict__ Dv)
{
  constexpr int NS = 48;   // K-steps of 64 over logical K=3072

  __shared__ __align__(16) ushort_t lds[2][4][8192];   // [buf][region][256*32]

  const int tid  = threadIdx.x;
  const int wave = tid >> 6, lane = tid & 63;
  const int wm = wave & 1, wn = wave >> 1;
  const int lr = lane & 15, kg = lane >> 4;

  // XCD-aware bijective swizzle (nwg=512, 512%8==0)
  const int bid = blockIdx.x;
  const int swz = (bid & 7) * 64 + (bid >> 3);
  const int m0 = (swz >> 2) * 256;     // 128 m-blocks
  const int n0 = (swz & 3) * 256;      // 4 n-blocks

  const ushort_t* Ac[3] = {Ah, Ah, Al};
  const ushort_t* Bc[3] = {Bh, Bl, Bh};

  f32x4 acc[8][4] = {};

  // stage one 16KiB region: part 0=A-ks0 1=B-ks0 2=A-ks1 3=B-ks1
  auto stage = [&](int s, int part) {
    if (s >= NS) return;
    const int comp = s >> 4;                          // 16 K-steps per component
    const int kk   = (s & 15) * 64 + (part >> 1) * 32;
    const ushort_t* g0 = (part & 1) ? Bc[comp] : Ac[comp];
    const int r0 = (part & 1) ? n0 : m0;
    #pragma unroll
    for (int c = 0; c < 2; ++c) {
      const int row = c * 128 + (tid >> 2);
      const int q   = (tid & 3) ^ ((row >> 1) & 3);
      const ushort_t* src = g0 + (size_t)(r0 + row) * CC + kk + q * 8;
      ushort_t* dst = &lds[s & 1][part][c * 4096 + wave * 512];  // wave-uniform
      GLOAD_LDS16(src, dst);
    }
  };
  auto rdA = [&](int b, int ks, int fm) -> short8 {
    const int row = wm * 128 + fm * 16 + lr;
    const int q   = kg ^ ((row >> 1) & 3);
    return *(const short8*)&lds[b][ks * 2][row * 32 + q * 8];
  };
  auto rdB = [&](int b, int ks, int fn) -> short8 {
    const int row = wn * 64 + fn * 16 + lr;
    const int q   = kg ^ ((row >> 1) & 3);
    return *(const short8*)&lds[b][ks * 2 + 1][row * 32 + q * 8];
  };

  // ---- prologue: [0,A0][0,B0][0,A1][0,B1][1,A0][1,B0]; oldest 2 regions landed
  stage(0, 0); stage(0, 1); stage(0, 2); stage(0, 3);
  stage(1, 0); stage(1, 1);
  asm volatile("s_waitcnt vmcnt(8)" ::: "memory");
  __builtin_amdgcn_sched_barrier(0);
  BARRIER();

  for (int s = 0; s < NS; ++s) {
    const int b = s & 1;
    short8 bfr[4], afr[4];

    // ---- P1: frags(B ks0, A m0-3 ks0); stage (s+1, A-ks1)
    #pragma unroll
    for (int fn = 0; fn < 4; ++fn) bfr[fn] = rdB(b, 0, fn);
    #pragma unroll
    for (int i = 0; i < 4; ++i) afr[i] = rdA(b, 0, i);
    stage(s + 1, 2);
    BARRIER();
    LGKM0();
    __builtin_amdgcn_s_setprio(1);
    #pragma unroll
    for (int i = 0; i < 4; ++i)
      #pragma unroll
      for (int fn = 0; fn < 4; ++fn)
        acc[i][fn] = __builtin_amdgcn_mfma_f32_16x16x32_bf16(afr[i], bfr[fn], acc[i][fn], 0, 0, 0);
    __builtin_amdgcn_s_setprio(0);
    BARRIER();

    // ---- P2: frags(A m4-7 ks0); stage (s+1, B-ks1); wait + barrier
    #pragma unroll
    for (int i = 0; i < 4; ++i) afr[i] = rdA(b, 0, 4 + i);
    stage(s + 1, 3);
    BARRIER();
    LGKM0();
    __builtin_amdgcn_s_setprio(1);
    #pragma unroll
    for (int i = 0; i < 4; ++i)
      #pragma unroll
      for (int fn = 0; fn < 4; ++fn)
        acc[4 + i][fn] = __builtin_amdgcn_mfma_f32_16x16x32_bf16(afr[i], bfr[fn], acc[4 + i][fn], 0, 0, 0);
    __builtin_amdgcn_s_setprio(0);
    if (s < NS - 1) { asm volatile("s_waitcnt vmcnt(8)" ::: "memory"); }
    else            { asm volatile("s_waitcnt vmcnt(0)" ::: "memory"); }
    __builtin_amdgcn_sched_barrier(0);
    BARRIER();

    // ---- P3: frags(B ks1, A m0-3 ks1); stage (s+2, A-ks0)
    #pragma unroll
    for (int fn = 0; fn < 4; ++fn) bfr[fn] = rdB(b, 1, fn);
    #pragma unroll
    for (int i = 0; i < 4; ++i) afr[i] = rdA(b, 1, i);
    stage(s + 2, 0);
    BARRIER();
    LGKM0();
    __builtin_amdgcn_s_setprio(1);
    #pragma unroll
    for (int i = 0; i < 4; ++i)
      #pragma unroll
      for (int fn = 0; fn < 4; ++fn)
        acc[i][fn] = __builtin_amdgcn_mfma_f32_16x16x32_bf16(afr[i], bfr[fn], acc[i][fn], 0, 0, 0);
    __builtin_amdgcn_s_setprio(0);
    BARRIER();

    // ---- P4: frags(A m4-7 ks1); stage (s+2, B-ks0); wait + barrier
    #pragma unroll
    for (int i = 0; i < 4; ++i) afr[i] = rdA(b, 1, 4 + i);
    stage(s + 2, 1);
    BARRIER();
    LGKM0();
    __builtin_amdgcn_s_setprio(1);
    #pragma unroll
    for (int i = 0; i < 4; ++i)
      #pragma unroll
      for (int fn = 0; fn < 4; ++fn)
        acc[4 + i][fn] = __builtin_amdgcn_mfma_f32_16x16x32_bf16(afr[i], bfr[fn], acc[4 + i][fn], 0, 0, 0);
    __builtin_amdgcn_s_setprio(0);
    if (s < NS - 2)       { asm volatile("s_waitcnt vmcnt(8)" ::: "memory"); }
    else if (s == NS - 2) { asm volatile("s_waitcnt vmcnt(4)" ::: "memory"); }
    __builtin_amdgcn_sched_barrier(0);
    BARRIER();
  }

  // ---- epilogue: C/D map col=lane&15, row=(lane>>4)*4+reg
  float*  Df = (float*)Dv;
  __half* Dh = (__half*)Dv;
  #pragma unroll
  for (int fm = 0; fm < 8; ++fm)
    #pragma unroll
    for (int fn = 0; fn < 4; ++fn) {
      const int col  = n0 + wn * 64 + fn * 16 + lr;
      const int rowb = m0 + wm * 128 + fm * 16 + kg * 4;
      #pragma unroll
      for (int r = 0; r < 4; ++r) {
        if (EPI == 0) Df[(size_t)(rowb + r) * CC + col] = acc[fm][fn][r];
        else          Dh[(size_t)(rowb + r) * CC + col] = __float2half(acc[fm][fn][r]);
      }
    }
}

// ---- WKV chunked scan (unchanged from round 4) ----
__global__ __launch_bounds__(256)
void wkv_phase_a(const float* __restrict__ kb, const __half* __restrict__ vb,
                 const float* __restrict__ decay,
                 float* __restrict__ SA, float* __restrict__ SB, float* __restrict__ SP)
{
  const int idx = blockIdx.x * 256 + threadIdx.x;
  const int c  = idx & (CC - 1);
  const int bc = idx >> 10;
  const int ch = bc & (NCH - 1);
  const int b  = bc >> 6;
  const float w = -__expf(decay[c]);
  float aa = 0.f, bb = 0.f, pp = -1e38f;
  size_t base = ((size_t)b * TT + (size_t)ch * CHL) * CC + c;
  #pragma unroll 4
  for (int t = 0; t < CHL; ++t) {
    const float kt = kb[base];
    const float vt = __half2float(vb[base]);
    const float q2 = fmaxf(pp + w, kt);
    const float f1 = __expf(pp + w - q2);
    const float f2 = __expf(kt - q2);
    aa = f1 * aa + f2 * vt; bb = f1 * bb + f2; pp = q2;
    base += CC;
  }
  SA[idx] = aa; SB[idx] = bb; SP[idx] = pp;
}

__global__ __launch_bounds__(256)
void wkv_combine(float* __restrict__ SA, float* __restrict__ SB, float* __restrict__ SP,
                 const float* __restrict__ decay)
{
  const int idx = blockIdx.x * 256 + threadIdx.x;
  const int c = idx & (CC - 1);
  const int b = idx >> 10;
  const float w  = -__expf(decay[c]);
  const float wL = w * (float)CHL;
  float aa = 0.f, bb = 0.f, pp = -1e38f;
  for (int ch = 0; ch < NCH; ++ch) {
    const size_t s = ((size_t)b * NCH + ch) * CC + c;
    const float la = SA[s], lb = SB[s], lp = SP[s];
    SA[s] = aa; SB[s] = bb; SP[s] = pp;
    const float pw = pp + wL;
    const float q  = fmaxf(pw, lp);
    const float e1 = __expf(pw - q);
    const float e2 = __expf(lp - q);
    aa = e1 * aa + e2 * la; bb = e1 * bb + e2 * lb; pp = q;
  }
}

__global__ __launch_bounds__(256)
void wkv_phase_c(const float* __restrict__ kb, const __half* __restrict__ vb,
                 const __half* __restrict__ rb, const float* __restrict__ decay,
                 const float* __restrict__ first,
                 const float* __restrict__ SA, const float* __restrict__ SB,
                 const float* __restrict__ SP,
                 ushort_t* __restrict__ yh, ushort_t* __restrict__ yl)
{
  const int idx = blockIdx.x * 256 + threadIdx.x;
  const int c  = idx & (CC - 1);
  const int bc = idx >> 10;
  const int ch = bc & (NCH - 1);
  const int b  = bc >> 6;
  const float w = -__expf(decay[c]);
  const float u = first[c];
  float aa = SA[idx], bb = SB[idx], pp = SP[idx];
  size_t base = ((size_t)b * TT + (size_t)ch * CHL) * CC + c;
  #pragma unroll 4
  for (int t = 0; t < CHL; ++t) {
    const float kt = kb[base];
    const float vt = __half2float(vb[base]);
    const float rt = __half2float(rb[base]);
    const float q  = fmaxf(pp, u + kt);
    const float e1 = __expf(pp - q);
    const float e2 = __expf(u + kt - q);
    const float yv = (e1 * aa + e2 * vt) / (e1 * bb + e2);
    const float sr = 1.f / (1.f + __expf(-rt));
    const float y  = sr * yv;
    const unsigned short h = f2bf(y);
    yh[base] = h;
    yl[base] = f2bf(y - bf2f(h));
    const float q2 = fmaxf(pp + w, kt);
    const float f1 = __expf(pp + w - q2);
    const float f2 = __expf(kt - q2);
    aa = f1 * aa + f2 * vt; bb = f1 * bb + f2; pp = q2;
    base += CC;
  }
}

extern "C" void kernel_launch(void* const* d_in, const int* in_sizes, int n_in,
                              void* d_out, int out_size, void* d_ws, size_t ws_size,
                              hipStream_t stream) {
  const float* x     = (const float*)d_in[0];
  const float* decay = (const float*)d_in[1];
  const float* first = (const float*)d_in[2];
  const float* mk    = (const float*)d_in[3];
  const float* mv    = (const float*)d_in[4];
  const float* mr    = (const float*)d_in[5];
  const float* Wk    = (const float*)d_in[6];
  const float* Wv    = (const float*)d_in[7];
  const float* Wr    = (const float*)d_in[8];
  const float* Wo    = (const float*)d_in[9];
  float* out = (float*)d_out;

  const size_t nbt = (size_t)BH * TT * CC;       // 33,554,432
  const size_t WS  = (size_t)CC * CC;            // 1,048,576
  // ws layout (bytes), total 425,721,856 == proven size:
  char* p = (char*)d_ws;
  float*    kbuf = (float*)   (p);                               // 134,217,728
  __half*   vbuf = (__half*)  (p + 134217728);                   //  67,108,864
  __half*   rbuf = (__half*)  (p + 201326592);                   //  67,108,864
  ushort_t* Asch = (ushort_t*)(p + 268435456);                   //  67,108,864 (Ah)
  ushort_t* Ascl = (ushort_t*)(p + 335544320);                   //  67,108,864 (Al)
  ushort_t* Wsp  = (ushort_t*)(p + 402653184);                   //  16,777,216 (8 bufs)
  float*    SA   = (float*)   (p + 419430400);
  float*    SB   = (float*)   (p + 421527552);
  float*    SP   = (float*)   (p + 423624704);

  dim3 blk(256);
  const dim3 ggrid(512), gblk(512);
  const unsigned lerpg = (unsigned)(nbt / 4 / 256);

  split_w<<<dim3(4 * CC * CC / 256), blk, 0, stream>>>(Wk, Wv, Wr, Wo, Wsp);

  lerp_split_one<<<lerpg, blk, 0, stream>>>(x, mk, Asch, Ascl);
  gemm_cat3<0><<<ggrid, gblk, 0, stream>>>(Asch, Ascl, Wsp + 0 * WS, Wsp + 1 * WS, kbuf);
  lerp_split_one<<<lerpg, blk, 0, stream>>>(x, mv, Asch, Ascl);
  gemm_cat3<1><<<ggrid, gblk, 0, stream>>>(Asch, Ascl, Wsp + 2 * WS, Wsp + 3 * WS, vbuf);
  lerp_split_one<<<lerpg, blk, 0, stream>>>(x, mr, Asch, Ascl);
  gemm_cat3<1><<<ggrid, gblk, 0, stream>>>(Asch, Ascl, Wsp + 4 * WS, Wsp + 5 * WS, rbuf);

  const int nscan = BH * NCH * CC;
  wkv_phase_a<<<dim3(nscan / 256), blk, 0, stream>>>(kbuf, vbuf, decay, SA, SB, SP);
  wkv_combine<<<dim3(BH * CC / 256), blk, 0, stream>>>(SA, SB, SP, decay);
  wkv_phase_c<<<dim3(nscan / 256), blk, 0, stream>>>(kbuf, vbuf, rbuf, decay, first,
                                                     SA, SB, SP, Asch, Ascl);

  gemm_cat3<0><<<ggrid, gblk, 0, stream>>>(Asch, Ascl, Wsp + 6 * WS, Wsp + 7 * WS, out);
}